// Round 11
// baseline (75.394 us; speedup 1.0000x reference)
//
#include <hip/hip_runtime.h>
#include <hip/hip_bf16.h>

#define TDEPTH 6
#define NLEAF 64
#define NGATE 63
#define INF 512
#define OUTF 512
#define BATCH 1024

#define BM 128
#define BN 64
#define SPLITK 16
#define THREADS 128
#define NPL 32        // planes per block (512/SPLITK)

typedef __attribute__((ext_vector_type(4)))  float f32x4;
typedef __attribute__((ext_vector_type(16))) float f32x16;
typedef __attribute__((ext_vector_type(8)))  __bf16 bf16x8;

__device__ __forceinline__ bf16x8 pack8(f32x4 a, f32x4 b) {
  bf16x8 w;
  w[0] = (__bf16)a[0]; w[1] = (__bf16)a[1];
  w[2] = (__bf16)a[2]; w[3] = (__bf16)a[3];
  w[4] = (__bf16)b[0]; w[5] = (__bf16)b[1];
  w[6] = (__bf16)b[2]; w[7] = (__bf16)b[3];
  return w;
}

// ---------------- kernel 1: leaf probs + pwb pack ----------------
// blocks [0,256): leaf.  blocks [256,8448): pack pw -> bf16 pwb, tiled
// per (nb, plane): 8KB tile = [32 LDS rows][16 granules]; granule G of
// row r holds pw[o = nb*64 + ((G^(r&15))>>3)*32 + r][i][k-granule (G^(r&15))&7]
// -> gemm stages tiles LINEARLY and reads with byte^((lo&15)<<4): conflict-free.
__global__ __launch_bounds__(256) void prep_kernel(
    const float* __restrict__ x, const float* __restrict__ gw,
    const float* __restrict__ gb, const float* __restrict__ pw,
    float* __restrict__ leaf, __bf16* __restrict__ pwb) {
  const int tid = threadIdx.x;
  if (blockIdx.x < 256) {
    const int wid = tid >> 6, lane = tid & 63;
    const int b = blockIdx.x * 4 + wid;
    __shared__ float g[4][NLEAF];
    if (lane < NGATE) {
      const float* xr = x + (size_t)b * INF;
      float a0 = 0.f, a1 = 0.f, a2 = 0.f, a3 = 0.f;
      #pragma unroll 4
      for (int i = 0; i < INF; i += 4) {
        a0 += xr[i + 0] * gw[(i + 0) * NGATE + lane];
        a1 += xr[i + 1] * gw[(i + 1) * NGATE + lane];
        a2 += xr[i + 2] * gw[(i + 2) * NGATE + lane];
        a3 += xr[i + 3] * gw[(i + 3) * NGATE + lane];
      }
      float t = (a0 + a1) + (a2 + a3) + gb[lane];
      g[wid][lane] = 1.0f / (1.0f + __expf(-t));
    }
    __syncthreads();
    float p = 1.0f;
    #pragma unroll
    for (int d = 0; d < TDEPTH; d++) {
      int prefix = lane >> (TDEPTH - 1 - d);
      int node = (1 << d) - 1 + (prefix >> 1);
      float gv = g[wid][node];
      p *= (prefix & 1) ? (1.0f - gv) : gv;
    }
    leaf[(size_t)b * NLEAF + lane] = p;
  } else {
    const unsigned Q = (blockIdx.x - 256) * 256 + tid;   // global granule
    const unsigned tile = Q >> 9;            // nb*512 + i
    const unsigned nb = tile >> 9, i = tile & 511;
    const unsigned q = Q & 511;              // granule within 8KB tile
    const unsigned r = ((q >> 7) << 3) + ((q >> 4) & 7);   // LDS row 0..31
    const unsigned v = (q & 15) ^ (r & 15);
    const unsigned o = nb * 64 + ((v >> 3) << 5) + r;
    const unsigned kg = v & 7;
    const float* src = pw + ((size_t)o * INF + i) * NLEAF + kg * 8;
    f32x4 a = *(const f32x4*)src, b = *(const f32x4*)(src + 4);
    *(bf16x8*)((char*)pwb + (size_t)Q * 16) = pack8(a, b);
  }
}

// async 16B global -> LDS (wave-uniform LDS base; +lane*16 implicit)
__device__ __forceinline__ void gload_lds16(const void* g, void* l) {
  __builtin_amdgcn_global_load_lds(
      (const __attribute__((address_space(1))) void*)g,
      (__attribute__((address_space(3))) void*)l, 16, 0, 0);
}

// ---------------- kernel 2: fused GEMM ----------------
// partial[s][b][o] = sum over K-slice of (x[b,i]*leaf[b,l]) * pw[o,i,l]
// 2 waves/block (128 thr), wave tile 64m x 64o, mfma_f32_32x32x16_bf16.
// 32 KB LDS -> 4 blocks/CU = 4 independent barrier groups; 3 x 8KB B-tiles
// (1 plane each), counted s_waitcnt vmcnt(4) (never 0 mid-loop).
__global__ __launch_bounds__(THREADS, 2) void gemm_kernel(
    const __bf16* __restrict__ pwb, const float* __restrict__ pb,
    const float* __restrict__ x, const float* __restrict__ leaf,
    float* __restrict__ partial) {
  __shared__ __align__(16) __bf16 Bsm[3][32 * 128];   // 3 x 8 KB
  __shared__ __align__(16) __bf16 xsm[NPL][BM];       // [plane][row], 8 KB

  const int tid = threadIdx.x, lane = tid & 63, w = tid >> 6;
  const int lo = lane & 31, half = lane >> 5;

  // XCD-chunked swizzle: chunk c = bid&7 covers all (mb,nb) for s in
  // {2c, 2c+1}: per-XCD pwb working set = 4 MB = L2; 8 mb-sharers adjacent.
  const int L = (blockIdx.x & 7) * 128 + (blockIdx.x >> 3);
  const int mb = L & 7;
  const int rest = L >> 3;
  const int nb = rest & 7, s = rest >> 3;
  const int m0 = mb * BM, n0 = nb * BN;
  const int cs = s * NPL;

  // resident leaf fragments: 2 m-subtiles x 32 f32 (this lane's k-half)
  f32x4 lf[2][4][2];
  #pragma unroll
  for (int mt = 0; mt < 2; mt++) {
    const float* lr =
        leaf + (size_t)(m0 + w * 64 + mt * 32 + lo) * NLEAF + half * 8;
    #pragma unroll
    for (int t4 = 0; t4 < 4; t4++) {
      lf[mt][t4][0] = *(const f32x4*)(lr + t4 * 16);
      lf[mt][t4][1] = *(const f32x4*)(lr + t4 * 16 + 4);
    }
  }

  // stage x slice -> bf16 [plane][row]: thread tid handles row tid
  {
    const float* src = x + (size_t)(m0 + tid) * INF + cs;
    #pragma unroll
    for (int c4 = 0; c4 < NPL / 4; c4++) {
      f32x4 v = *(const f32x4*)(src + c4 * 4);
      #pragma unroll
      for (int j = 0; j < 4; j++) xsm[c4 * 4 + j][tid] = (__bf16)v[j];
    }
  }

  const char* pwc = (const char*)pwb;
  const size_t tbase = (size_t)(nb * 512 + cs) << 13;   // first tile, 8KB each

  auto stage = [&](char* dstb, int t) {
    const char* srcb = pwc + tbase + ((size_t)t << 13);
    #pragma unroll
    for (int j = 0; j < 4; j++)
      gload_lds16(srcb + j * 2048 + tid * 16, dstb + j * 2048 + w * 1024);
  };

  f32x16 acc00 = (f32x16)(0.f), acc01 = (f32x16)(0.f);
  f32x16 acc10 = (f32x16)(0.f), acc11 = (f32x16)(0.f);
  const unsigned swz = (unsigned)(lo & 15) << 4;

  auto do_step = [&](const char* bufc, int t) {
    const float xv0 = (float)xsm[t][w * 64 + lo];
    const float xv1 = (float)xsm[t][w * 64 + 32 + lo];
    #pragma unroll
    for (int t4 = 0; t4 < 4; t4++) {
      const unsigned kb0 = ((unsigned)(t4 * 32 + half * 16)) ^ swz;
      const unsigned kb1 = ((unsigned)(128 + t4 * 32 + half * 16)) ^ swz;
      bf16x8 bf0 = *(const bf16x8*)(bufc + lo * 256 + kb0);
      bf16x8 bf1 = *(const bf16x8*)(bufc + lo * 256 + kb1);
      f32x4 p0a = lf[0][t4][0] * xv0, p0b = lf[0][t4][1] * xv0;
      f32x4 p1a = lf[1][t4][0] * xv1, p1b = lf[1][t4][1] * xv1;
      bf16x8 a0 = pack8(p0a, p0b);
      bf16x8 a1 = pack8(p1a, p1b);
      acc00 = __builtin_amdgcn_mfma_f32_32x32x16_bf16(a0, bf0, acc00, 0, 0, 0);
      acc01 = __builtin_amdgcn_mfma_f32_32x32x16_bf16(a0, bf1, acc01, 0, 0, 0);
      acc10 = __builtin_amdgcn_mfma_f32_32x32x16_bf16(a1, bf0, acc10, 0, 0, 0);
      acc11 = __builtin_amdgcn_mfma_f32_32x32x16_bf16(a1, bf1, acc11, 0, 0, 0);
    }
  };

  char* bA = (char*)&Bsm[0][0];
  char* bB = (char*)&Bsm[1][0];
  char* bC = (char*)&Bsm[2][0];

  // prologue: stage 0,1; full drain once (x ds_writes + stage 0); barrier
  stage(bA, 0);
  stage(bB, 1);
  __builtin_amdgcn_sched_barrier(0);
  asm volatile("s_waitcnt vmcnt(4) lgkmcnt(0)" ::: "memory");
  __builtin_amdgcn_s_barrier();
  __builtin_amdgcn_sched_barrier(0);

  // main loop: counted vmcnt(4) — stage(t+2)'s 4 loads stay in flight
  for (int t = 0; t < NPL - 2; ++t) {
    stage(bC, t + 2);
    do_step(bA, t);
    __builtin_amdgcn_sched_barrier(0);
    asm volatile("s_waitcnt vmcnt(4) lgkmcnt(0)" ::: "memory");
    __builtin_amdgcn_s_barrier();
    __builtin_amdgcn_sched_barrier(0);
    char* tmp = bA; bA = bB; bB = bC; bC = tmp;
  }
  do_step(bA, NPL - 2);
  __builtin_amdgcn_sched_barrier(0);
  asm volatile("s_waitcnt vmcnt(0) lgkmcnt(0)" ::: "memory");
  __builtin_amdgcn_s_barrier();
  __builtin_amdgcn_sched_barrier(0);
  do_step(bB, NPL - 1);

  // bias contribution (s == SPLITK-1 only): A = leaf (x==1), W = pb direct
  if (s == SPLITK - 1) {
    #pragma unroll
    for (int t4 = 0; t4 < 4; t4++) {
      bf16x8 a0 = pack8(lf[0][t4][0], lf[0][t4][1]);
      bf16x8 a1 = pack8(lf[1][t4][0], lf[1][t4][1]);
      #pragma unroll
      for (int nt = 0; nt < 2; nt++) {
        const float* pr =
            pb + (size_t)(n0 + nt * 32 + lo) * NLEAF + t4 * 16 + half * 8;
        f32x4 c0 = *(const f32x4*)pr, c1 = *(const f32x4*)(pr + 4);
        bf16x8 bb = pack8(c0, c1);
        if (nt == 0) {
          acc00 = __builtin_amdgcn_mfma_f32_32x32x16_bf16(a0, bb, acc00, 0, 0, 0);
          acc10 = __builtin_amdgcn_mfma_f32_32x32x16_bf16(a1, bb, acc10, 0, 0, 0);
        } else {
          acc01 = __builtin_amdgcn_mfma_f32_32x32x16_bf16(a0, bb, acc01, 0, 0, 0);
          acc11 = __builtin_amdgcn_mfma_f32_32x32x16_bf16(a1, bb, acc11, 0, 0, 0);
        }
      }
    }
  }

  // epilogue: partial[s]; D row = (e&3)+8*(e>>2)+4*half, col = lo
  #pragma unroll
  for (int mt = 0; mt < 2; mt++) {
    float* dst =
        partial + ((size_t)s * BATCH + m0 + w * 64 + mt * 32) * OUTF + n0;
    #pragma unroll
    for (int e = 0; e < 16; e++) {
      int row = (e & 3) + 8 * (e >> 2) + 4 * half;
      if (mt == 0) {
        dst[(size_t)row * OUTF + lo] = acc00[e];
        dst[(size_t)row * OUTF + 32 + lo] = acc01[e];
      } else {
        dst[(size_t)row * OUTF + lo] = acc10[e];
        dst[(size_t)row * OUTF + 32 + lo] = acc11[e];
      }
    }
  }
}

// ---------------- kernel 3: split-K reduce ----------------
__global__ __launch_bounds__(256) void reduce_kernel(
    const float* __restrict__ partial, float* __restrict__ out) {
  size_t e = ((size_t)blockIdx.x * 256 + threadIdx.x) * 4;
  f32x4 sum = (f32x4){0.f, 0.f, 0.f, 0.f};
  #pragma unroll
  for (int s = 0; s < SPLITK; s++)
    sum += *(const f32x4*)(partial + (size_t)s * BATCH * OUTF + e);
  *(f32x4*)(out + e) = sum;
}

extern "C" void kernel_launch(void* const* d_in, const int* in_sizes, int n_in,
                              void* d_out, int out_size, void* d_ws, size_t ws_size,
                              hipStream_t stream) {
  const float* x  = (const float*)d_in[0];
  const float* gw = (const float*)d_in[1];
  const float* gb = (const float*)d_in[2];
  const float* pw = (const float*)d_in[3];
  const float* pb = (const float*)d_in[4];
  float* out = (float*)d_out;

  float*  leaf    = (float*)d_ws;                          // 256 KB
  __bf16* pwb     = (__bf16*)((char*)d_ws + (1 << 20));    // 32 MB
  float*  partial = (float*)((char*)d_ws + (33ull << 20)); // 32 MB

  prep_kernel<<<256 + 8192, 256, 0, stream>>>(x, gw, gb, pw, leaf, pwb);
  gemm_kernel<<<8 * 8 * SPLITK, THREADS, 0, stream>>>(pwb, pb, x, leaf, partial);
  reduce_kernel<<<(BATCH * OUTF) / (256 * 4), 256, 0, stream>>>(partial, out);
}